// Round 1
// baseline (1557.525 us; speedup 1.0000x reference)
//
#include <hip/hip_runtime.h>

// SpikingMultiHeadAttention — fp32, B=2, S=2048, D=1024, H=16, hd=64
// out_size = B*S*D + B*H*S*S (out, then attn, concatenated flat)
// Round 0: correctness-first fp32 tiled kernels (no MFMA yet).
//   - spike(scores*scale) == (raw_scores > 0), so the scale is skipped.
//   - Q/K/scores kept in fp32: the Heaviside threshold is sign-sensitive;
//     bf16 would flip ~1e5+ attn bits and blow the out tolerance.

#define SEQ 2048
#define DIM 1024
#define NH 16
#define HD 64
#define BATCH 2
#define MROWS (BATCH * SEQ)   // 4096
#define BHT (BATCH * NH)      // 32

__device__ __forceinline__ void fma4x4(const float4& a, const float4& b, float acc[4][4]) {
    float av[4] = {a.x, a.y, a.z, a.w};
    float bv[4] = {b.x, b.y, b.z, b.w};
#pragma unroll
    for (int i = 0; i < 4; ++i)
#pragma unroll
        for (int j = 0; j < 4; ++j)
            acc[i][j] = fmaf(av[i], bv[j], acc[i][j]);
}

// C = X @ W.T + bias   (X:[M=4096,K=1024], W:[N=1024,K=1024] row-major, bias:[N])
// LOAD_MODE  0: X plain row-major [M,K]
//            1: X gathered from BHSD layout [B,H,S,hd] (for ctx -> out proj)
// STORE_MODE 0: C plain row-major [M,N]
//            1: C scattered to BHSD layout (for q/k/v head split)
template <int LOAD_MODE, int STORE_MODE>
__global__ __launch_bounds__(256) void gemm_xwT(const float* __restrict__ X,
                                                const float* __restrict__ W,
                                                const float* __restrict__ bias,
                                                float* __restrict__ C) {
    __shared__ float Xs[16][64];  // [k][m]
    __shared__ float Ws[16][64];  // [k][n]
    const int t = threadIdx.x;
    const int tx = t & 15, ty = t >> 4;
    const int m0 = blockIdx.y * 64;
    const int n0 = blockIdx.x * 64;
    const int lr = t >> 2;       // 0..63: row within 64-tile
    const int lc = (t & 3) * 4;  // 0,4,8,12: k within 16-tile

    float acc[4][4] = {};
    for (int kt = 0; kt < DIM; kt += 16) {
        float4 xv;
        if (LOAD_MODE == 0) {
            xv = *(const float4*)&X[(size_t)(m0 + lr) * DIM + kt + lc];
        } else {
            int m = m0 + lr;
            int b = m >> 11, s = m & 2047;
            int d = kt + lc;
            int h = d >> 6, hdi = d & 63;  // lc stride 4 never crosses a 64-boundary mid-vector
            xv = *(const float4*)&X[((((size_t)b * NH + h) * SEQ + s) << 6) + hdi];
        }
        float4 wv = *(const float4*)&W[(size_t)(n0 + lr) * DIM + kt + lc];
        __syncthreads();  // protect previous iteration's LDS reads
        Xs[lc + 0][lr] = xv.x; Xs[lc + 1][lr] = xv.y; Xs[lc + 2][lr] = xv.z; Xs[lc + 3][lr] = xv.w;
        Ws[lc + 0][lr] = wv.x; Ws[lc + 1][lr] = wv.y; Ws[lc + 2][lr] = wv.z; Ws[lc + 3][lr] = wv.w;
        __syncthreads();
#pragma unroll
        for (int kk = 0; kk < 16; ++kk) {
            float4 a = *(const float4*)&Xs[kk][ty * 4];
            float4 b = *(const float4*)&Ws[kk][tx * 4];
            fma4x4(a, b, acc);
        }
    }

    float4 bv4 = *(const float4*)&bias[n0 + tx * 4];
    float bb[4] = {bv4.x, bv4.y, bv4.z, bv4.w};
#pragma unroll
    for (int i = 0; i < 4; ++i) {
        float4 o;
        o.x = acc[i][0] + bb[0];
        o.y = acc[i][1] + bb[1];
        o.z = acc[i][2] + bb[2];
        o.w = acc[i][3] + bb[3];
        int m = m0 + ty * 4 + i;
        int n = n0 + tx * 4;
        if (STORE_MODE == 0) {
            *(float4*)&C[(size_t)m * DIM + n] = o;
        } else {
            int b = m >> 11, s = m & 2047;
            int h = n >> 6, hdi = n & 63;
            *(float4*)&C[((((size_t)b * NH + h) * SEQ + s) << 6) + hdi] = o;
        }
    }
}

// Fused attention: per (bh, 64-q-tile) block, loop over 64-k-tiles:
//   S = Q Kt (fp32), spike -> write attn tile + stage in LDS, ctx += S @ V.
__global__ __launch_bounds__(256) void attn_fused(const float* __restrict__ Q,
                                                  const float* __restrict__ K,
                                                  const float* __restrict__ V,
                                                  float* __restrict__ attn,
                                                  float* __restrict__ CTX) {
    __shared__ float Qs[64][64];  // [d][q]
    __shared__ float Ks[64][64];  // [d][k]
    __shared__ float Vs[64][64];  // [k][hd]
    __shared__ float Ss[64][64];  // [k][q]
    const int t = threadIdx.x;
    const int tx = t & 15, ty = t >> 4;
    const int m0 = ty * 4, n0 = tx * 4;
    const int bh = blockIdx.y;
    const int q0 = blockIdx.x * 64;
    const size_t qbase = ((size_t)bh * SEQ + q0) * HD;

    {
        int r = t >> 4;           // 0..15
        int c = (t & 15) * 4;     // 0..60
#pragma unroll
        for (int i = 0; i < 4; ++i) {
            float4 v4 = *(const float4*)&Q[qbase + (size_t)(r + 16 * i) * HD + c];
            Qs[c + 0][r + 16 * i] = v4.x;
            Qs[c + 1][r + 16 * i] = v4.y;
            Qs[c + 2][r + 16 * i] = v4.z;
            Qs[c + 3][r + 16 * i] = v4.w;
        }
    }

    float ctx[4][4] = {};
    for (int kt = 0; kt < SEQ; kt += 64) {
        __syncthreads();  // previous phase-2 done with Ks/Vs/Ss
        {
            int r = t >> 4;
            int c = (t & 15) * 4;
            size_t kbase = ((size_t)bh * SEQ + kt) * HD;
#pragma unroll
            for (int i = 0; i < 4; ++i) {
                float4 kv = *(const float4*)&K[kbase + (size_t)(r + 16 * i) * HD + c];
                Ks[c + 0][r + 16 * i] = kv.x;
                Ks[c + 1][r + 16 * i] = kv.y;
                Ks[c + 2][r + 16 * i] = kv.z;
                Ks[c + 3][r + 16 * i] = kv.w;
                float4 vv = *(const float4*)&V[kbase + (size_t)(r + 16 * i) * HD + c];
                *(float4*)&Vs[r + 16 * i][c] = vv;
            }
        }
        __syncthreads();

        // phase 1: scores (fp32) over hd=64
        float s[4][4] = {};
#pragma unroll 8
        for (int d = 0; d < 64; ++d) {
            float4 a = *(const float4*)&Qs[d][m0];
            float4 b = *(const float4*)&Ks[d][n0];
            fma4x4(a, b, s);
        }
        // spike, write attn tile (rows q, cols k) straight from registers,
        // and stage k-major into LDS for the ctx GEMM
#pragma unroll
        for (int i = 0; i < 4; ++i) {
            float4 o;
            o.x = s[i][0] > 0.f ? 1.f : 0.f;
            o.y = s[i][1] > 0.f ? 1.f : 0.f;
            o.z = s[i][2] > 0.f ? 1.f : 0.f;
            o.w = s[i][3] > 0.f ? 1.f : 0.f;
            *(float4*)&attn[((size_t)bh * SEQ + (q0 + m0 + i)) * SEQ + kt + n0] = o;
            Ss[n0 + 0][m0 + i] = o.x;
            Ss[n0 + 1][m0 + i] = o.y;
            Ss[n0 + 2][m0 + i] = o.z;
            Ss[n0 + 3][m0 + i] = o.w;
        }
        __syncthreads();

        // phase 2: ctx += S(q,k) @ V(k,hd)
#pragma unroll 8
        for (int kk = 0; kk < 64; ++kk) {
            float4 a = *(const float4*)&Ss[kk][m0];
            float4 v4 = *(const float4*)&Vs[kk][n0];
            fma4x4(a, v4, ctx);
        }
    }

#pragma unroll
    for (int i = 0; i < 4; ++i) {
        float4 o;
        o.x = ctx[i][0]; o.y = ctx[i][1]; o.z = ctx[i][2]; o.w = ctx[i][3];
        *(float4*)&CTX[qbase + (size_t)(m0 + i) * HD + n0] = o;
    }
}

extern "C" void kernel_launch(void* const* d_in, const int* in_sizes, int n_in,
                              void* d_out, int out_size, void* d_ws, size_t ws_size,
                              hipStream_t stream) {
    const float* query = (const float*)d_in[0];
    const float* key   = (const float*)d_in[1];
    const float* value = (const float*)d_in[2];
    const float* Wq = (const float*)d_in[3];
    const float* bq = (const float*)d_in[4];
    const float* Wk = (const float*)d_in[5];
    const float* bk = (const float*)d_in[6];
    const float* Wv = (const float*)d_in[7];
    const float* bv = (const float*)d_in[8];
    const float* Wo = (const float*)d_in[9];
    const float* bo = (const float*)d_in[10];

    float* out  = (float*)d_out;
    float* attn = out + (size_t)MROWS * DIM;  // output 1 right after output 0

    float* Qb   = (float*)d_ws;               // [B,H,S,hd] each = 4,194,304 floats
    float* Kb   = Qb + (size_t)MROWS * DIM;
    float* Vb   = Kb + (size_t)MROWS * DIM;
    float* CTXb = Vb + (size_t)MROWS * DIM;   // total 64 MB of d_ws

    dim3 blk(256);
    dim3 g(DIM / 64, MROWS / 64);  // 16 x 64

    hipLaunchKernelGGL((gemm_xwT<0, 1>), g, blk, 0, stream, query, Wq, bq, Qb);
    hipLaunchKernelGGL((gemm_xwT<0, 1>), g, blk, 0, stream, key,   Wk, bk, Kb);
    hipLaunchKernelGGL((gemm_xwT<0, 1>), g, blk, 0, stream, value, Wv, bv, Vb);

    dim3 ga(SEQ / 64, BHT);  // 32 x 32
    hipLaunchKernelGGL(attn_fused, ga, blk, 0, stream, Qb, Kb, Vb, attn, CTXb);

    hipLaunchKernelGGL((gemm_xwT<1, 0>), g, blk, 0, stream, CTXb, Wo, bo, out);
}

// Round 2
// 1098.748 us; speedup vs baseline: 1.4175x; 1.4175x over previous
//
#include <hip/hip_runtime.h>

// SpikingMultiHeadAttention — B=2, S=2048, D=1024, H=16, hd=64, fp32 I/O.
// Round 2: split-bf16 MFMA everywhere.
//   - spike(scores*scale) == (raw > 0): scale skipped.
//   - Sign-critical chain (Q-proj, K-proj, QK^T) uses hi/lo bf16 pairs:
//     x ~= hi + lo with |x-hi-lo| <= 2^-17|x|; products keep hi*hi + hi*lo
//     + lo*hi (3 MFMA passes) -> score error ~5e-5 abs vs score std ~8.
//   - V path / ctx / out-proj: plain bf16 MFMA (smooth ~0.05 abs error on out).
//   - attn values are exactly 1.0/0.0.
// MFMA 16x16x32 bf16 layouts (HW-verified per guide):
//   A-frag: lane holds A[m=lane&15][k=(lane>>4)*8+j], j=0..7 (8 consec k)
//   B-frag: lane holds Bt[n=lane&15][k=(lane>>4)*8+j]  (Bt = [N][K] storage)
//   C/D:    lane,reg r -> row m=(lane>>4)*4+r, col n=lane&15

#define SEQ 2048
#define DIM 1024
#define NH 16
#define HD 64
#define BATCH 2
#define MROWS (BATCH * SEQ)   // 4096
#define BHT (BATCH * NH)      // 32

typedef __attribute__((ext_vector_type(8))) short short8;
typedef __attribute__((ext_vector_type(4))) float f4;

__device__ __forceinline__ f4 mfma16(short8 a, short8 b, f4 c) {
    return __builtin_amdgcn_mfma_f32_16x16x32_bf16(a, b, c, 0, 0, 0);
}
__device__ __forceinline__ unsigned short rne16(float x) {
    union { float f; unsigned u; } a; a.f = x;
    return (unsigned short)((a.u + 0x7fffu + ((a.u >> 16) & 1u)) >> 16);
}
// x ~= hi + lo: hi = truncate-to-bf16(x) (exact residual), lo = rne-bf16(x-hi)
__device__ __forceinline__ void split2(float x, unsigned short& h, unsigned short& l) {
    union { float f; unsigned u; } a; a.f = x;
    unsigned hu = a.u & 0xffff0000u;
    h = (unsigned short)(hu >> 16);
    union { unsigned u; float f; } hb; hb.u = hu;
    l = rne16(x - hb.f);
}
__device__ __forceinline__ short8 ld8(const unsigned short* p) { return *(const short8*)p; }

// ---------- weight conversion ----------
__global__ __launch_bounds__(256) void wsplit(const float* __restrict__ W,
                                              unsigned short* __restrict__ hi,
                                              unsigned short* __restrict__ lo) {
    int i = (blockIdx.x * 256 + threadIdx.x) * 4;
    float4 w = *(const float4*)&W[i];
    float xs[4] = {w.x, w.y, w.z, w.w};
#pragma unroll
    for (int j = 0; j < 4; ++j) {
        unsigned short h, l;
        split2(xs[j], h, l);
        hi[i + j] = h;
        lo[i + j] = l;
    }
}
__global__ __launch_bounds__(256) void wb16(const float* __restrict__ W,
                                            unsigned short* __restrict__ o) {
    int i = (blockIdx.x * 256 + threadIdx.x) * 4;
    float4 w = *(const float4*)&W[i];
    o[i + 0] = rne16(w.x); o[i + 1] = rne16(w.y);
    o[i + 2] = rne16(w.z); o[i + 3] = rne16(w.w);
}

// ---------- Q/K projection: q = X @ W.T + b, 3-pass split, store hi/lo ----------
// wave tile 32m x 64n; block = 4 waves -> 128m x 64n; grid (32 m, 16 n)
__global__ __launch_bounds__(256) void proj_qk(const float* __restrict__ X,
                                               const unsigned short* __restrict__ Whi,
                                               const unsigned short* __restrict__ Wlo,
                                               const float* __restrict__ bias,
                                               unsigned short* __restrict__ Ohi,
                                               unsigned short* __restrict__ Olo) {
    const int t = threadIdx.x, wave = t >> 6, lane = t & 63;
    const int la = lane & 15, qd = lane >> 4;
    const int m0 = blockIdx.x * 128 + wave * 32;
    const int n0 = blockIdx.y * 64;

    f4 acc[2][4] = {};
    for (int k0 = 0; k0 < DIM; k0 += 32) {
        short8 ahi[2], alo[2];
#pragma unroll
        for (int ms = 0; ms < 2; ++ms) {
            const float* ap = &X[(size_t)(m0 + ms * 16 + la) * DIM + k0 + qd * 8];
            float4 x0 = *(const float4*)ap;
            float4 x1 = *(const float4*)(ap + 4);
            float xs[8] = {x0.x, x0.y, x0.z, x0.w, x1.x, x1.y, x1.z, x1.w};
#pragma unroll
            for (int j = 0; j < 8; ++j) {
                unsigned short h, l;
                split2(xs[j], h, l);
                ahi[ms][j] = (short)h;
                alo[ms][j] = (short)l;
            }
        }
#pragma unroll
        for (int ns = 0; ns < 4; ++ns) {
            size_t wi = (size_t)(n0 + ns * 16 + la) * DIM + k0 + qd * 8;
            short8 bhi = ld8(&Whi[wi]);
            short8 blo = ld8(&Wlo[wi]);
#pragma unroll
            for (int ms = 0; ms < 2; ++ms) {
                acc[ms][ns] = mfma16(alo[ms], bhi, acc[ms][ns]);
                acc[ms][ns] = mfma16(ahi[ms], blo, acc[ms][ns]);
                acc[ms][ns] = mfma16(ahi[ms], bhi, acc[ms][ns]);
            }
        }
    }
#pragma unroll
    for (int ns = 0; ns < 4; ++ns) {
        int n = n0 + ns * 16 + la;
        float bv = bias[n];
        int h = n >> 6, d = n & 63;
#pragma unroll
        for (int ms = 0; ms < 2; ++ms)
#pragma unroll
            for (int r = 0; r < 4; ++r) {
                int m = m0 + ms * 16 + qd * 4 + r;
                int b = m >> 11, s = m & 2047;
                unsigned short hh, ll;
                split2(acc[ms][ns][r] + bv, hh, ll);
                size_t o = ((size_t)(b * NH + h) * SEQ + s) * HD + d;
                Ohi[o] = hh;
                Olo[o] = ll;
            }
    }
}

// ---------- V projection: v = X @ W.T + b, bf16, store transposed [bh][hd][S] ----------
// wave tile 64m x 64n; block 256m x 64n; grid (16 m, 16 n)
__global__ __launch_bounds__(256) void proj_v(const float* __restrict__ X,
                                              const unsigned short* __restrict__ Wb,
                                              const float* __restrict__ bias,
                                              unsigned short* __restrict__ Vt) {
    __shared__ unsigned short Ts[4][64][72];
    const int t = threadIdx.x, wave = t >> 6, lane = t & 63;
    const int la = lane & 15, qd = lane >> 4;
    const int m0 = blockIdx.x * 256 + wave * 64;
    const int n0 = blockIdx.y * 64;

    f4 acc[4][4] = {};
    for (int k0 = 0; k0 < DIM; k0 += 32) {
        short8 a[4];
#pragma unroll
        for (int ms = 0; ms < 4; ++ms) {
            const float* ap = &X[(size_t)(m0 + ms * 16 + la) * DIM + k0 + qd * 8];
            float4 x0 = *(const float4*)ap;
            float4 x1 = *(const float4*)(ap + 4);
            float xs[8] = {x0.x, x0.y, x0.z, x0.w, x1.x, x1.y, x1.z, x1.w};
#pragma unroll
            for (int j = 0; j < 8; ++j) a[ms][j] = (short)rne16(xs[j]);
        }
#pragma unroll
        for (int ns = 0; ns < 4; ++ns) {
            short8 wb = ld8(&Wb[(size_t)(n0 + ns * 16 + la) * DIM + k0 + qd * 8]);
#pragma unroll
            for (int ms = 0; ms < 4; ++ms) acc[ms][ns] = mfma16(a[ms], wb, acc[ms][ns]);
        }
    }
    // epilogue: transpose through LDS, store [bh][d][s] coalesced along s
#pragma unroll
    for (int ns = 0; ns < 4; ++ns) {
        float bv = bias[n0 + ns * 16 + la];
#pragma unroll
        for (int ms = 0; ms < 4; ++ms)
#pragma unroll
            for (int r = 0; r < 4; ++r)
                Ts[wave][ns * 16 + la][ms * 16 + qd * 4 + r] = rne16(acc[ms][ns][r] + bv);
    }
    __syncthreads();
    int b = m0 >> 11, s0 = m0 & 2047, h = n0 >> 6;
    size_t vbase = (size_t)(b * NH + h) * HD * SEQ;
#pragma unroll
    for (int it = 0; it < 4; ++it) {
        int c = it * 64 + lane;        // 0..255
        int d = c >> 2, sc = (c & 3) * 16;
        short8 v0 = *(const short8*)&Ts[wave][d][sc];
        short8 v1 = *(const short8*)&Ts[wave][d][sc + 8];
        *(short8*)&Vt[vbase + (size_t)d * SEQ + s0 + sc] = v0;
        *(short8*)&Vt[vbase + (size_t)d * SEQ + s0 + sc + 8] = v1;
    }
}

// ---------- fused attention: scores (3-pass split) -> spike -> attn + ctx ----------
// grid (32 bh, 16 qblocks); block 4 waves; wave = 32 q rows; k-tiles of 64
__global__ __launch_bounds__(256) void attn_mfma(const unsigned short* __restrict__ Qhi,
                                                 const unsigned short* __restrict__ Qlo,
                                                 const unsigned short* __restrict__ Khi,
                                                 const unsigned short* __restrict__ Klo,
                                                 const unsigned short* __restrict__ Vt,
                                                 float* __restrict__ attn,
                                                 unsigned short* __restrict__ ctxb) {
    __shared__ unsigned short Ps[128][72];
    const int t = threadIdx.x, wave = t >> 6, lane = t & 63;
    const int la = lane & 15, qd = lane >> 4;
    const int bh = blockIdx.x;
    const int q0 = blockIdx.y * 128 + wave * 32;

    short8 qhi[2][2], qlo[2][2];
#pragma unroll
    for (int ms = 0; ms < 2; ++ms)
#pragma unroll
        for (int ks = 0; ks < 2; ++ks) {
            size_t qi = ((size_t)bh * SEQ + q0 + ms * 16 + la) * HD + ks * 32 + qd * 8;
            qhi[ms][ks] = ld8(&Qhi[qi]);
            qlo[ms][ks] = ld8(&Qlo[qi]);
        }

    f4 cacc[2][4] = {};
    for (int kt = 0; kt < SEQ; kt += 64) {
        f4 s[2][4] = {};
#pragma unroll
        for (int ns = 0; ns < 4; ++ns)
#pragma unroll
            for (int ks = 0; ks < 2; ++ks) {
                size_t ki = ((size_t)bh * SEQ + kt + ns * 16 + la) * HD + ks * 32 + qd * 8;
                short8 khi = ld8(&Khi[ki]);
                short8 klo = ld8(&Klo[ki]);
#pragma unroll
                for (int ms = 0; ms < 2; ++ms) {
                    s[ms][ns] = mfma16(qlo[ms][ks], khi, s[ms][ns]);
                    s[ms][ns] = mfma16(qhi[ms][ks], klo, s[ms][ns]);
                    s[ms][ns] = mfma16(qhi[ms][ks], khi, s[ms][ns]);
                }
            }
        // spike: write attn (fp32) from C-layout regs + stage P (bf16) to LDS
#pragma unroll
        for (int ms = 0; ms < 2; ++ms)
#pragma unroll
            for (int ns = 0; ns < 4; ++ns)
#pragma unroll
                for (int r = 0; r < 4; ++r) {
                    bool pos = s[ms][ns][r] > 0.f;
                    int qrow = q0 + ms * 16 + qd * 4 + r;
                    attn[((size_t)bh * SEQ + qrow) * SEQ + kt + ns * 16 + la] = pos ? 1.f : 0.f;
                    Ps[wave * 32 + ms * 16 + qd * 4 + r][ns * 16 + la] =
                        pos ? (unsigned short)0x3f80 : (unsigned short)0;
                }
        __syncthreads();
        // ctx += P @ V   (P exact in bf16; Vt rows are B-frags)
#pragma unroll
        for (int ks = 0; ks < 2; ++ks) {
            short8 pa[2];
#pragma unroll
            for (int ms = 0; ms < 2; ++ms)
                pa[ms] = *(const short8*)&Ps[wave * 32 + ms * 16 + la][ks * 32 + qd * 8];
#pragma unroll
            for (int ns = 0; ns < 4; ++ns) {
                short8 vb = ld8(&Vt[((size_t)bh * HD + ns * 16 + la) * SEQ + kt + ks * 32 + qd * 8]);
#pragma unroll
                for (int ms = 0; ms < 2; ++ms) cacc[ms][ns] = mfma16(pa[ms], vb, cacc[ms][ns]);
            }
        }
        __syncthreads();
    }
#pragma unroll
    for (int ns = 0; ns < 4; ++ns)
#pragma unroll
        for (int ms = 0; ms < 2; ++ms)
#pragma unroll
            for (int r = 0; r < 4; ++r) {
                int qrow = q0 + ms * 16 + qd * 4 + r;
                ctxb[((size_t)bh * SEQ + qrow) * HD + ns * 16 + la] = rne16(cacc[ms][ns][r]);
            }
}

// ---------- out projection: out = ctx @ Wo.T + bo (bf16 MFMA, fp32 out) ----------
// wave tile 32m x 64n; block 128m x 64n; grid (32 m, 16 n)
__global__ __launch_bounds__(256) void proj_out(const unsigned short* __restrict__ Ctx,
                                                const unsigned short* __restrict__ Wb,
                                                const float* __restrict__ bias,
                                                float* __restrict__ out) {
    const int t = threadIdx.x, wave = t >> 6, lane = t & 63;
    const int la = lane & 15, qd = lane >> 4;
    const int m0 = blockIdx.x * 128 + wave * 32;
    const int n0 = blockIdx.y * 64;

    f4 acc[2][4] = {};
    for (int k0 = 0; k0 < DIM; k0 += 32) {
        short8 a[2];
#pragma unroll
        for (int ms = 0; ms < 2; ++ms) {
            int m = m0 + ms * 16 + la;
            int b = m >> 11, s = m & 2047;
            int k = k0 + qd * 8;
            int h = k >> 6, d = k & 63;
            a[ms] = ld8(&Ctx[((size_t)(b * NH + h) * SEQ + s) * HD + d]);
        }
#pragma unroll
        for (int ns = 0; ns < 4; ++ns) {
            short8 wb = ld8(&Wb[(size_t)(n0 + ns * 16 + la) * DIM + k0 + qd * 8]);
#pragma unroll
            for (int ms = 0; ms < 2; ++ms) acc[ms][ns] = mfma16(a[ms], wb, acc[ms][ns]);
        }
    }
#pragma unroll
    for (int ns = 0; ns < 4; ++ns) {
        int n = n0 + ns * 16 + la;
        float bv = bias[n];
#pragma unroll
        for (int ms = 0; ms < 2; ++ms)
#pragma unroll
            for (int r = 0; r < 4; ++r) {
                int m = m0 + ms * 16 + qd * 4 + r;
                out[(size_t)m * DIM + n] = acc[ms][ns][r] + bv;
            }
    }
}

extern "C" void kernel_launch(void* const* d_in, const int* in_sizes, int n_in,
                              void* d_out, int out_size, void* d_ws, size_t ws_size,
                              hipStream_t stream) {
    const float* query = (const float*)d_in[0];
    const float* key   = (const float*)d_in[1];
    const float* value = (const float*)d_in[2];
    const float* Wq = (const float*)d_in[3];
    const float* bq = (const float*)d_in[4];
    const float* Wk = (const float*)d_in[5];
    const float* bk = (const float*)d_in[6];
    const float* Wv = (const float*)d_in[7];
    const float* bv = (const float*)d_in[8];
    const float* Wo = (const float*)d_in[9];
    const float* bo = (const float*)d_in[10];

    float* out  = (float*)d_out;
    float* attn = out + (size_t)MROWS * DIM;

    const size_t NE = (size_t)MROWS * DIM;  // 4,194,304
    const size_t WE = (size_t)DIM * DIM;    // 1,048,576
    unsigned short* Qhi = (unsigned short*)d_ws;
    unsigned short* Qlo = Qhi + NE;
    unsigned short* Khi = Qlo + NE;
    unsigned short* Klo = Khi + NE;
    unsigned short* Vt  = Klo + NE;
    unsigned short* Ctx = Vt + NE;
    unsigned short* Wqh = Ctx + NE;
    unsigned short* Wql = Wqh + WE;
    unsigned short* Wkh = Wql + WE;
    unsigned short* Wkl = Wkh + WE;
    unsigned short* Wvb = Wkl + WE;
    unsigned short* Wob = Wvb + WE;   // end: ~62.9 MB

    dim3 blk(256);
    hipLaunchKernelGGL(wsplit, dim3(WE / 1024), blk, 0, stream, Wq, Wqh, Wql);
    hipLaunchKernelGGL(wsplit, dim3(WE / 1024), blk, 0, stream, Wk, Wkh, Wkl);
    hipLaunchKernelGGL(wb16,   dim3(WE / 1024), blk, 0, stream, Wv, Wvb);
    hipLaunchKernelGGL(wb16,   dim3(WE / 1024), blk, 0, stream, Wo, Wob);

    hipLaunchKernelGGL(proj_qk, dim3(32, 16), blk, 0, stream, query, Wqh, Wql, bq, Qhi, Qlo);
    hipLaunchKernelGGL(proj_qk, dim3(32, 16), blk, 0, stream, key,   Wkh, Wkl, bk, Khi, Klo);
    hipLaunchKernelGGL(proj_v,  dim3(16, 16), blk, 0, stream, value, Wvb, bv, Vt);

    hipLaunchKernelGGL(attn_mfma, dim3(32, 16), blk, 0, stream, Qhi, Qlo, Khi, Klo, Vt, attn, Ctx);

    hipLaunchKernelGGL(proj_out, dim3(32, 16), blk, 0, stream, Ctx, Wob, bo, out);
}

// Round 4
// 1086.218 us; speedup vs baseline: 1.4339x; 1.0115x over previous
//
#include <hip/hip_runtime.h>

// SpikingMultiHeadAttention — B=2, S=2048, D=1024, H=16, hd=64, fp32 I/O.
// Round 4: r2 pipeline + barrier-free LDS + coalesced attn stores.
//   - ws budget: 52 MiB (r3's 68 MiB overflowed ws -> replay corruption).
//     Ctx overlays dead Wq/Wk split weights (stream-ordered reuse).
//   - spike(scores*scale) == (raw > 0): scale skipped.
//   - Sign chain (Q/K proj, QK^T) in hi/lo bf16 pairs, 3 MFMA passes.
//   - attn tile written via Ps LDS readback as dwordx4 (was 32 scalar stores).
// MFMA 16x16x32 bf16 layouts (HW-verified):
//   A-frag: lane holds A[m=lane&15][k=(lane>>4)*8+j], j=0..7
//   B-frag: lane holds Bt[n=lane&15][k=(lane>>4)*8+j]
//   C/D:    lane,reg r -> row m=(lane>>4)*4+r, col n=lane&15

#define SEQ 2048
#define DIM 1024
#define NH 16
#define HD 64
#define BATCH 2
#define MROWS (BATCH * SEQ)   // 4096
#define BHT (BATCH * NH)      // 32

typedef __attribute__((ext_vector_type(8))) short short8;
typedef __attribute__((ext_vector_type(4))) float f4;
typedef unsigned short ushort;

__device__ __forceinline__ f4 mfma16(short8 a, short8 b, f4 c) {
    return __builtin_amdgcn_mfma_f32_16x16x32_bf16(a, b, c, 0, 0, 0);
}
__device__ __forceinline__ ushort rne16(float x) {
    union { float f; unsigned u; } a; a.f = x;
    return (ushort)((a.u + 0x7fffu + ((a.u >> 16) & 1u)) >> 16);
}
// x ~= hi + lo: hi = truncate-to-bf16(x), lo = rne-bf16(x - hi)
__device__ __forceinline__ void split2(float x, ushort& h, ushort& l) {
    union { float f; unsigned u; } a; a.f = x;
    unsigned hu = a.u & 0xffff0000u;
    h = (ushort)(hu >> 16);
    union { unsigned u; float f; } hb; hb.u = hu;
    l = rne16(x - hb.f);
}
__device__ __forceinline__ short8 ld8(const ushort* p) { return *(const short8*)p; }

// ---------- weight conversion ----------
__global__ __launch_bounds__(256) void ksplit(const float* __restrict__ X,
                                              ushort* __restrict__ hi,
                                              ushort* __restrict__ lo) {
    int i = (blockIdx.x * 256 + threadIdx.x) * 4;
    float4 w = *(const float4*)&X[i];
    float xs[4] = {w.x, w.y, w.z, w.w};
    ushort h[4], l[4];
#pragma unroll
    for (int j = 0; j < 4; ++j) split2(xs[j], h[j], l[j]);
    *(short4*)&hi[i] = make_short4(h[0], h[1], h[2], h[3]);
    *(short4*)&lo[i] = make_short4(l[0], l[1], l[2], l[3]);
}
__global__ __launch_bounds__(256) void kb16(const float* __restrict__ X,
                                            ushort* __restrict__ o) {
    int i = (blockIdx.x * 256 + threadIdx.x) * 4;
    float4 w = *(const float4*)&X[i];
    *(short4*)&o[i] = make_short4(rne16(w.x), rne16(w.y), rne16(w.z), rne16(w.w));
}

// ---------- Q/K projection: O = X @ W.T + b (3-pass split), store hi/lo BHSD ----
// wave tile 32m x 64n; block 128m x 64n; grid (32 m, 16 n). X split in-kernel.
__global__ __launch_bounds__(256) void proj_qk(const float* __restrict__ X,
                                               const ushort* __restrict__ Whi,
                                               const ushort* __restrict__ Wlo,
                                               const float* __restrict__ bias,
                                               ushort* __restrict__ Ohi,
                                               ushort* __restrict__ Olo) {
    const int t = threadIdx.x, wave = t >> 6, lane = t & 63;
    const int la = lane & 15, qd = lane >> 4;
    const int m0 = blockIdx.x * 128 + wave * 32;
    const int n0 = blockIdx.y * 64;

    f4 acc[2][4] = {};
    for (int k0 = 0; k0 < DIM; k0 += 32) {
        short8 ahi[2], alo[2];
#pragma unroll
        for (int ms = 0; ms < 2; ++ms) {
            const float* ap = &X[(size_t)(m0 + ms * 16 + la) * DIM + k0 + qd * 8];
            float4 x0 = *(const float4*)ap;
            float4 x1 = *(const float4*)(ap + 4);
            float xs[8] = {x0.x, x0.y, x0.z, x0.w, x1.x, x1.y, x1.z, x1.w};
#pragma unroll
            for (int j = 0; j < 8; ++j) {
                ushort h, l;
                split2(xs[j], h, l);
                ahi[ms][j] = (short)h;
                alo[ms][j] = (short)l;
            }
        }
#pragma unroll
        for (int ns = 0; ns < 4; ++ns) {
            size_t wi = (size_t)(n0 + ns * 16 + la) * DIM + k0 + qd * 8;
            short8 bhi = ld8(&Whi[wi]);
            short8 blo = ld8(&Wlo[wi]);
#pragma unroll
            for (int ms = 0; ms < 2; ++ms) {
                acc[ms][ns] = mfma16(alo[ms], bhi, acc[ms][ns]);
                acc[ms][ns] = mfma16(ahi[ms], blo, acc[ms][ns]);
                acc[ms][ns] = mfma16(ahi[ms], bhi, acc[ms][ns]);
            }
        }
    }
#pragma unroll
    for (int ns = 0; ns < 4; ++ns) {
        int n = n0 + ns * 16 + la;
        float bv = bias[n];
        int h = n >> 6, d = n & 63;
#pragma unroll
        for (int ms = 0; ms < 2; ++ms)
#pragma unroll
            for (int r = 0; r < 4; ++r) {
                int m = m0 + ms * 16 + qd * 4 + r;
                int b = m >> 11, s = m & 2047;
                ushort hh, ll;
                split2(acc[ms][ns][r] + bv, hh, ll);
                size_t o = ((size_t)(b * NH + h) * SEQ + s) * HD + d;
                Ohi[o] = hh;
                Olo[o] = ll;
            }
    }
}

// ---------- V projection: bf16, store transposed [bh][hd][S] ----------
// wave tile 64m x 64n; block 256m x 64n; grid (16 m, 16 n)
__global__ __launch_bounds__(256) void proj_v(const float* __restrict__ X,
                                              const ushort* __restrict__ Wb,
                                              const float* __restrict__ bias,
                                              ushort* __restrict__ Vt) {
    __shared__ ushort Ts[4][64][72];   // per-wave private [wave][n][m]
    const int t = threadIdx.x, wave = t >> 6, lane = t & 63;
    const int la = lane & 15, qd = lane >> 4;
    const int m0 = blockIdx.x * 256 + wave * 64;
    const int n0 = blockIdx.y * 64;

    f4 acc[4][4] = {};
    for (int k0 = 0; k0 < DIM; k0 += 32) {
        short8 a[4];
#pragma unroll
        for (int ms = 0; ms < 4; ++ms) {
            const float* ap = &X[(size_t)(m0 + ms * 16 + la) * DIM + k0 + qd * 8];
            float4 x0 = *(const float4*)ap;
            float4 x1 = *(const float4*)(ap + 4);
            float xs[8] = {x0.x, x0.y, x0.z, x0.w, x1.x, x1.y, x1.z, x1.w};
#pragma unroll
            for (int j = 0; j < 8; ++j) a[ms][j] = (short)rne16(xs[j]);
        }
#pragma unroll
        for (int ns = 0; ns < 4; ++ns) {
            short8 wb = ld8(&Wb[(size_t)(n0 + ns * 16 + la) * DIM + k0 + qd * 8]);
#pragma unroll
            for (int ms = 0; ms < 4; ++ms) acc[ms][ns] = mfma16(a[ms], wb, acc[ms][ns]);
        }
    }
#pragma unroll
    for (int ns = 0; ns < 4; ++ns) {
        float bv = bias[n0 + ns * 16 + la];
#pragma unroll
        for (int ms = 0; ms < 4; ++ms)
#pragma unroll
            for (int r = 0; r < 4; ++r)
                Ts[wave][ns * 16 + la][ms * 16 + qd * 4 + r] = rne16(acc[ms][ns][r] + bv);
    }
    // same-wave LDS round-trip: lgkmcnt-ordered, no barrier needed
    int b = m0 >> 11, s0 = m0 & 2047, h = n0 >> 6;
    size_t vbase = (size_t)(b * NH + h) * HD * SEQ;
#pragma unroll
    for (int it = 0; it < 4; ++it) {
        int c = it * 64 + lane;
        int d = c >> 2, sc = (c & 3) * 16;
        short8 v0 = *(const short8*)&Ts[wave][d][sc];
        short8 v1 = *(const short8*)&Ts[wave][d][sc + 8];
        *(short8*)&Vt[vbase + (size_t)d * SEQ + s0 + sc] = v0;
        *(short8*)&Vt[vbase + (size_t)d * SEQ + s0 + sc + 8] = v1;
    }
}

// ---------- fused attention: 3-pass split scores -> spike -> attn + ctx ----------
// grid (32 bh, 16 qblocks); 4 waves/block; wave = 32 q rows; k-tiles of 64.
// Ps rows are per-wave private -> no barriers. attn written via Ps readback
// as fully-coalesced dwordx4 (8 stores/kt/wave instead of 32).
__global__ __launch_bounds__(256) void attn_mfma(const ushort* __restrict__ Qhi,
                                                 const ushort* __restrict__ Qlo,
                                                 const ushort* __restrict__ Khi,
                                                 const ushort* __restrict__ Klo,
                                                 const ushort* __restrict__ Vt,
                                                 float* __restrict__ attn,
                                                 ushort* __restrict__ ctxb) {
    __shared__ ushort Ps[128][72];
    const int t = threadIdx.x, wave = t >> 6, lane = t & 63;
    const int la = lane & 15, qd = lane >> 4;
    const int bh = blockIdx.x;
    const int q0 = blockIdx.y * 128 + wave * 32;

    short8 qhi[2][2], qlo[2][2];
#pragma unroll
    for (int ms = 0; ms < 2; ++ms)
#pragma unroll
        for (int ks = 0; ks < 2; ++ks) {
            size_t qi = ((size_t)bh * SEQ + q0 + ms * 16 + la) * HD + ks * 32 + qd * 8;
            qhi[ms][ks] = ld8(&Qhi[qi]);
            qlo[ms][ks] = ld8(&Qlo[qi]);
        }

    f4 cacc[2][4] = {};
    for (int kt = 0; kt < SEQ; kt += 64) {
        f4 s[2][4] = {};
#pragma unroll
        for (int ns = 0; ns < 4; ++ns)
#pragma unroll
            for (int ks = 0; ks < 2; ++ks) {
                size_t ki = ((size_t)bh * SEQ + kt + ns * 16 + la) * HD + ks * 32 + qd * 8;
                short8 khi = ld8(&Khi[ki]);
                short8 klo = ld8(&Klo[ki]);
#pragma unroll
                for (int ms = 0; ms < 2; ++ms) {
                    s[ms][ns] = mfma16(qlo[ms][ks], khi, s[ms][ns]);
                    s[ms][ns] = mfma16(qhi[ms][ks], klo, s[ms][ns]);
                    s[ms][ns] = mfma16(qhi[ms][ks], khi, s[ms][ns]);
                }
            }
        // spike -> Ps (bf16 1.0/0.0), per-wave private rows
#pragma unroll
        for (int ms = 0; ms < 2; ++ms)
#pragma unroll
            for (int ns = 0; ns < 4; ++ns)
#pragma unroll
                for (int r = 0; r < 4; ++r)
                    Ps[wave * 32 + ms * 16 + qd * 4 + r][ns * 16 + la] =
                        s[ms][ns][r] > 0.f ? (ushort)0x3f80 : (ushort)0;
        // attn tile: read Ps back as short4, widen bf16->fp32 by <<16, dwordx4 store
#pragma unroll
        for (int i = 0; i < 8; ++i) {
            int row = i * 4 + qd;  // 0..31, each wave-row once across the quad
            short4 p = *(const short4*)&Ps[wave * 32 + row][la * 4];
            float4 o;
            o.x = __uint_as_float(((unsigned)(ushort)p.x) << 16);
            o.y = __uint_as_float(((unsigned)(ushort)p.y) << 16);
            o.z = __uint_as_float(((unsigned)(ushort)p.z) << 16);
            o.w = __uint_as_float(((unsigned)(ushort)p.w) << 16);
            *(float4*)&attn[((size_t)bh * SEQ + q0 + row) * SEQ + kt + la * 4] = o;
        }
        // ctx += P @ V (same-wave LDS round-trip)
#pragma unroll
        for (int ks = 0; ks < 2; ++ks) {
            short8 pa[2];
#pragma unroll
            for (int ms = 0; ms < 2; ++ms)
                pa[ms] = *(const short8*)&Ps[wave * 32 + ms * 16 + la][ks * 32 + qd * 8];
#pragma unroll
            for (int ns = 0; ns < 4; ++ns) {
                short8 vb = ld8(&Vt[((size_t)bh * HD + ns * 16 + la) * SEQ + kt + ks * 32 + qd * 8]);
#pragma unroll
                for (int ms = 0; ms < 2; ++ms) cacc[ms][ns] = mfma16(pa[ms], vb, cacc[ms][ns]);
            }
        }
    }
#pragma unroll
    for (int ns = 0; ns < 4; ++ns)
#pragma unroll
        for (int ms = 0; ms < 2; ++ms)
#pragma unroll
            for (int r = 0; r < 4; ++r) {
                int qrow = q0 + ms * 16 + qd * 4 + r;
                ctxb[((size_t)bh * SEQ + qrow) * HD + ns * 16 + la] = rne16(cacc[ms][ns][r]);
            }
}

// ---------- out projection: out = ctx @ Wo.T + bo ----------
// wave tile 32m x 64n; block 128m x 64n; grid (32 m, 16 n)
__global__ __launch_bounds__(256) void proj_out(const ushort* __restrict__ Ctx,
                                                const ushort* __restrict__ Wb,
                                                const float* __restrict__ bias,
                                                float* __restrict__ out) {
    const int t = threadIdx.x, wave = t >> 6, lane = t & 63;
    const int la = lane & 15, qd = lane >> 4;
    const int m0 = blockIdx.x * 128 + wave * 32;
    const int n0 = blockIdx.y * 64;

    f4 acc[2][4] = {};
    for (int k0 = 0; k0 < DIM; k0 += 32) {
        short8 a[2];
#pragma unroll
        for (int ms = 0; ms < 2; ++ms) {
            int m = m0 + ms * 16 + la;
            int b = m >> 11, s = m & 2047;
            int k = k0 + qd * 8;
            int h = k >> 6, d = k & 63;
            a[ms] = ld8(&Ctx[((size_t)(b * NH + h) * SEQ + s) * HD + d]);
        }
#pragma unroll
        for (int ns = 0; ns < 4; ++ns) {
            short8 wb = ld8(&Wb[(size_t)(n0 + ns * 16 + la) * DIM + k0 + qd * 8]);
#pragma unroll
            for (int ms = 0; ms < 2; ++ms) acc[ms][ns] = mfma16(a[ms], wb, acc[ms][ns]);
        }
    }
#pragma unroll
    for (int ns = 0; ns < 4; ++ns) {
        int n = n0 + ns * 16 + la;
        float bv = bias[n];
#pragma unroll
        for (int ms = 0; ms < 2; ++ms)
#pragma unroll
            for (int r = 0; r < 4; ++r) {
                int m = m0 + ms * 16 + qd * 4 + r;
                out[(size_t)m * DIM + n] = acc[ms][ns][r] + bv;
            }
    }
}

extern "C" void kernel_launch(void* const* d_in, const int* in_sizes, int n_in,
                              void* d_out, int out_size, void* d_ws, size_t ws_size,
                              hipStream_t stream) {
    const float* query = (const float*)d_in[0];
    const float* key   = (const float*)d_in[1];
    const float* value = (const float*)d_in[2];
    const float* Wq = (const float*)d_in[3];
    const float* bq = (const float*)d_in[4];
    const float* Wk = (const float*)d_in[5];
    const float* bk = (const float*)d_in[6];
    const float* Wv = (const float*)d_in[7];
    const float* bv = (const float*)d_in[8];
    const float* Wo = (const float*)d_in[9];
    const float* bo = (const float*)d_in[10];

    float* out  = (float*)d_out;
    float* attn = out + (size_t)MROWS * DIM;

    const size_t NE = (size_t)MROWS * DIM;  // 4,194,304
    const size_t WE = (size_t)DIM * DIM;    // 1,048,576
    ushort* Qhi = (ushort*)d_ws;            // 5 x NE = 40 MiB
    ushort* Qlo = Qhi + NE;
    ushort* Khi = Qlo + NE;
    ushort* Klo = Khi + NE;
    ushort* Vt  = Klo + NE;
    ushort* Wqh = Vt + NE;                  // 6 x WE = 12 MiB -> total 52 MiB
    ushort* Wql = Wqh + WE;
    ushort* Wkh = Wql + WE;
    ushort* Wkl = Wkh + WE;
    ushort* Wvb = Wkl + WE;
    ushort* Wob = Wvb + WE;
    ushort* Ctx = Wqh;                      // overlays Wqh..Wkl (4 WE = NE), dead by then

    dim3 blk(256);
    hipLaunchKernelGGL(ksplit, dim3(WE / 1024), blk, 0, stream, Wq, Wqh, Wql);
    hipLaunchKernelGGL(ksplit, dim3(WE / 1024), blk, 0, stream, Wk, Wkh, Wkl);
    hipLaunchKernelGGL(kb16,   dim3(WE / 1024), blk, 0, stream, Wv, Wvb);
    hipLaunchKernelGGL(kb16,   dim3(WE / 1024), blk, 0, stream, Wo, Wob);

    hipLaunchKernelGGL(proj_qk, dim3(32, 16), blk, 0, stream, query, Wqh, Wql, bq, Qhi, Qlo);
    hipLaunchKernelGGL(proj_qk, dim3(32, 16), blk, 0, stream, key,   Wkh, Wkl, bk, Khi, Klo);
    hipLaunchKernelGGL(proj_v,  dim3(16, 16), blk, 0, stream, value, Wvb, bv, Vt);

    hipLaunchKernelGGL(attn_mfma, dim3(32, 16), blk, 0, stream, Qhi, Qlo, Khi, Klo, Vt, attn, Ctx);

    hipLaunchKernelGGL(proj_out, dim3(32, 16), blk, 0, stream, Ctx, Wob, bo, out);
}

// Round 5
// 1042.075 us; speedup vs baseline: 1.4946x; 1.0424x over previous
//
#include <hip/hip_runtime.h>

// SpikingMultiHeadAttention — B=2, S=2048, D=1024, H=16, hd=64, fp32 I/O.
// Round 5: register double-buffered (software-pipelined) loads in all GEMM
// loops + fused qkv projection (grid.z) + fused weight conversion.
//   - spike(scores*scale) == (raw > 0): scale skipped.
//   - Sign chain (Q/K proj, QK^T) in hi/lo bf16 pairs, 3 MFMA passes,
//     accumulation order bit-identical to r4 (absmax must stay 1.75).
// MFMA 16x16x32 bf16 layouts (HW-verified):
//   A-frag: lane holds A[m=lane&15][k=(lane>>4)*8+j], j=0..7
//   B-frag: lane holds Bt[n=lane&15][k=(lane>>4)*8+j]
//   C/D:    lane,reg r -> row m=(lane>>4)*4+r, col n=lane&15

#define SEQ 2048
#define DIM 1024
#define NH 16
#define HD 64
#define BATCH 2
#define MROWS (BATCH * SEQ)   // 4096
#define BHT (BATCH * NH)      // 32

typedef __attribute__((ext_vector_type(8))) short short8;
typedef __attribute__((ext_vector_type(4))) float f4;
typedef unsigned short ushort;

__device__ __forceinline__ f4 mfma16(short8 a, short8 b, f4 c) {
    return __builtin_amdgcn_mfma_f32_16x16x32_bf16(a, b, c, 0, 0, 0);
}
__device__ __forceinline__ ushort rne16(float x) {
    union { float f; unsigned u; } a; a.f = x;
    return (ushort)((a.u + 0x7fffu + ((a.u >> 16) & 1u)) >> 16);
}
// x ~= hi + lo: hi = truncate-to-bf16(x), lo = rne-bf16(x - hi)
__device__ __forceinline__ void split2(float x, ushort& h, ushort& l) {
    union { float f; unsigned u; } a; a.f = x;
    unsigned hu = a.u & 0xffff0000u;
    h = (ushort)(hu >> 16);
    union { unsigned u; float f; } hb; hb.u = hu;
    l = rne16(x - hb.f);
}
__device__ __forceinline__ short8 ld8(const ushort* p) { return *(const short8*)p; }

// ---------- fused weight conversion: 4 jobs on grid.y ----------
__global__ __launch_bounds__(256) void wconv(const float* __restrict__ Wq,
                                             const float* __restrict__ Wk,
                                             const float* __restrict__ Wv,
                                             const float* __restrict__ Wo,
                                             ushort* __restrict__ Wqh, ushort* __restrict__ Wql,
                                             ushort* __restrict__ Wkh, ushort* __restrict__ Wkl,
                                             ushort* __restrict__ Wvb, ushort* __restrict__ Wob) {
    int i = (blockIdx.x * 256 + threadIdx.x) * 4;
    int job = blockIdx.y;
    const float* src = job == 0 ? Wq : job == 1 ? Wk : job == 2 ? Wv : Wo;
    float4 w = *(const float4*)&src[i];
    float xs[4] = {w.x, w.y, w.z, w.w};
    if (job < 2) {
        ushort h[4], l[4];
#pragma unroll
        for (int j = 0; j < 4; ++j) split2(xs[j], h[j], l[j]);
        ushort* ph = job ? Wkh : Wqh;
        ushort* pl = job ? Wkl : Wql;
        *(short4*)&ph[i] = make_short4(h[0], h[1], h[2], h[3]);
        *(short4*)&pl[i] = make_short4(l[0], l[1], l[2], l[3]);
    } else {
        ushort* po = job == 2 ? Wvb : Wob;
        *(short4*)&po[i] = make_short4(rne16(xs[0]), rne16(xs[1]), rne16(xs[2]), rne16(xs[3]));
    }
}

// ---------- fused q/k/v projection (grid.z selects), pipelined loads ----------
template <int B>
__device__ __forceinline__ void ld_qk(const float* __restrict__ X, const ushort* __restrict__ Wh,
                                      const ushort* __restrict__ Wl, int m0, int n0, int la, int qd,
                                      int k0, float4 (&xA)[2][2][2], short8 (&wH)[2][4],
                                      short8 (&wL)[2][4]) {
#pragma unroll
    for (int ms = 0; ms < 2; ++ms) {
        const float* ap = &X[(size_t)(m0 + ms * 16 + la) * DIM + k0 + qd * 8];
        xA[B][ms][0] = *(const float4*)ap;
        xA[B][ms][1] = *(const float4*)(ap + 4);
    }
#pragma unroll
    for (int ns = 0; ns < 4; ++ns) {
        size_t wi = (size_t)(n0 + ns * 16 + la) * DIM + k0 + qd * 8;
        wH[B][ns] = ld8(&Wh[wi]);
        wL[B][ns] = ld8(&Wl[wi]);
    }
}

template <int B>
__device__ __forceinline__ void fma_qk(float4 (&xA)[2][2][2], short8 (&wH)[2][4],
                                       short8 (&wL)[2][4], f4 (&acc)[2][4]) {
    short8 ahi[2], alo[2];
#pragma unroll
    for (int ms = 0; ms < 2; ++ms) {
        float xs[8] = {xA[B][ms][0].x, xA[B][ms][0].y, xA[B][ms][0].z, xA[B][ms][0].w,
                       xA[B][ms][1].x, xA[B][ms][1].y, xA[B][ms][1].z, xA[B][ms][1].w};
#pragma unroll
        for (int j = 0; j < 8; ++j) {
            ushort h, l;
            split2(xs[j], h, l);
            ahi[ms][j] = (short)h;
            alo[ms][j] = (short)l;
        }
    }
#pragma unroll
    for (int ns = 0; ns < 4; ++ns)
#pragma unroll
        for (int ms = 0; ms < 2; ++ms) {
            acc[ms][ns] = mfma16(alo[ms], wH[B][ns], acc[ms][ns]);
            acc[ms][ns] = mfma16(ahi[ms], wL[B][ns], acc[ms][ns]);
            acc[ms][ns] = mfma16(ahi[ms], wH[B][ns], acc[ms][ns]);
        }
}

template <int B>
__device__ __forceinline__ void ld_v(const float* __restrict__ X, const ushort* __restrict__ Wb,
                                     int m0, int n0, int la, int qd, int k0,
                                     float4 (&xA)[2][2][2], short8 (&wH)[2][4]) {
#pragma unroll
    for (int ms = 0; ms < 2; ++ms) {
        const float* ap = &X[(size_t)(m0 + ms * 16 + la) * DIM + k0 + qd * 8];
        xA[B][ms][0] = *(const float4*)ap;
        xA[B][ms][1] = *(const float4*)(ap + 4);
    }
#pragma unroll
    for (int ns = 0; ns < 4; ++ns)
        wH[B][ns] = ld8(&Wb[(size_t)(n0 + ns * 16 + la) * DIM + k0 + qd * 8]);
}

template <int B>
__device__ __forceinline__ void fma_v(float4 (&xA)[2][2][2], short8 (&wH)[2][4], f4 (&acc)[2][4]) {
    short8 a[2];
#pragma unroll
    for (int ms = 0; ms < 2; ++ms) {
        float xs[8] = {xA[B][ms][0].x, xA[B][ms][0].y, xA[B][ms][0].z, xA[B][ms][0].w,
                       xA[B][ms][1].x, xA[B][ms][1].y, xA[B][ms][1].z, xA[B][ms][1].w};
#pragma unroll
        for (int j = 0; j < 8; ++j) a[ms][j] = (short)rne16(xs[j]);
    }
#pragma unroll
    for (int ns = 0; ns < 4; ++ns)
#pragma unroll
        for (int ms = 0; ms < 2; ++ms) acc[ms][ns] = mfma16(a[ms], wH[B][ns], acc[ms][ns]);
}

__global__ __launch_bounds__(256, 2) void proj_qkv(
    const float* __restrict__ query, const float* __restrict__ key, const float* __restrict__ value,
    const ushort* __restrict__ Wqh, const ushort* __restrict__ Wql,
    const ushort* __restrict__ Wkh, const ushort* __restrict__ Wkl,
    const ushort* __restrict__ Wvb,
    const float* __restrict__ bq, const float* __restrict__ bk, const float* __restrict__ bv,
    ushort* __restrict__ Qhi, ushort* __restrict__ Qlo,
    ushort* __restrict__ Khi, ushort* __restrict__ Klo, ushort* __restrict__ Vt) {
    const int z = blockIdx.z;
    const int t = threadIdx.x, wave = t >> 6, lane = t & 63;
    const int la = lane & 15, qd = lane >> 4;
    const int m0 = blockIdx.x * 128 + wave * 32;
    const int n0 = blockIdx.y * 64;

    float4 xA[2][2][2];
    short8 wH[2][4], wL[2][4];
    f4 acc[2][4] = {};

    if (z < 2) {
        const float* X = z ? key : query;
        const ushort* Wh = z ? Wkh : Wqh;
        const ushort* Wl = z ? Wkl : Wql;
        ld_qk<0>(X, Wh, Wl, m0, n0, la, qd, 0, xA, wH, wL);
        for (int k0 = 0; k0 < DIM; k0 += 64) {
            ld_qk<1>(X, Wh, Wl, m0, n0, la, qd, k0 + 32, xA, wH, wL);
            fma_qk<0>(xA, wH, wL, acc);
            ld_qk<0>(X, Wh, Wl, m0, n0, la, qd, (k0 + 64) & (DIM - 1), xA, wH, wL);
            fma_qk<1>(xA, wH, wL, acc);
        }
        const float* bias = z ? bk : bq;
        ushort* Oh = z ? Khi : Qhi;
        ushort* Ol = z ? Klo : Qlo;
#pragma unroll
        for (int ns = 0; ns < 4; ++ns) {
            int n = n0 + ns * 16 + la;
            float bvv = bias[n];
            int h = n >> 6, d = n & 63;
#pragma unroll
            for (int ms = 0; ms < 2; ++ms)
#pragma unroll
                for (int r = 0; r < 4; ++r) {
                    int m = m0 + ms * 16 + qd * 4 + r;
                    int b = m >> 11, s = m & 2047;
                    ushort hh, ll;
                    split2(acc[ms][ns][r] + bvv, hh, ll);
                    size_t o = ((size_t)(b * NH + h) * SEQ + s) * HD + d;
                    Oh[o] = hh;
                    Ol[o] = ll;
                }
        }
    } else {
        __shared__ ushort Ts[4][64][40];  // per-wave private [wave][d][m], 16B-aligned rows
        ld_v<0>(value, Wvb, m0, n0, la, qd, 0, xA, wH);
        for (int k0 = 0; k0 < DIM; k0 += 64) {
            ld_v<1>(value, Wvb, m0, n0, la, qd, k0 + 32, xA, wH);
            fma_v<0>(xA, wH, acc);
            ld_v<0>(value, Wvb, m0, n0, la, qd, (k0 + 64) & (DIM - 1), xA, wH);
            fma_v<1>(xA, wH, acc);
        }
#pragma unroll
        for (int ns = 0; ns < 4; ++ns) {
            float bvv = bv[n0 + ns * 16 + la];
#pragma unroll
            for (int ms = 0; ms < 2; ++ms)
#pragma unroll
                for (int r = 0; r < 4; ++r)
                    Ts[wave][ns * 16 + la][ms * 16 + qd * 4 + r] = rne16(acc[ms][ns][r] + bvv);
        }
        // same-wave LDS round-trip (lgkmcnt-ordered, wave-private region)
        int b = m0 >> 11, s0 = m0 & 2047, h = n0 >> 6;
        size_t vbase = (size_t)(b * NH + h) * HD * SEQ;
#pragma unroll
        for (int it = 0; it < 4; ++it) {
            int d = it * 16 + (lane >> 2), sc = (lane & 3) * 8;
            short8 v0 = *(const short8*)&Ts[wave][d][sc];
            *(short8*)&Vt[vbase + (size_t)d * SEQ + s0 + sc] = v0;
        }
    }
}

// ---------- fused attention, 32-col half-tiles, pipelined loads ----------
template <int B>
__device__ __forceinline__ void ld_at(const ushort* __restrict__ Khi, const ushort* __restrict__ Klo,
                                      const ushort* __restrict__ Vt, int bh, int c0, int la, int qd,
                                      short8 (&kH)[2][2][2], short8 (&kL)[2][2][2],
                                      short8 (&vB)[2][4]) {
#pragma unroll
    for (int n2 = 0; n2 < 2; ++n2)
#pragma unroll
        for (int ks = 0; ks < 2; ++ks) {
            size_t ki = ((size_t)bh * SEQ + c0 + n2 * 16 + la) * HD + ks * 32 + qd * 8;
            kH[B][n2][ks] = ld8(&Khi[ki]);
            kL[B][n2][ks] = ld8(&Klo[ki]);
        }
#pragma unroll
    for (int ns = 0; ns < 4; ++ns)
        vB[B][ns] = ld8(&Vt[((size_t)bh * HD + ns * 16 + la) * SEQ + c0 + qd * 8]);
}

template <int B>
__device__ __forceinline__ void half_at(ushort (*Ps)[40], float* __restrict__ attn,
                                        int bh, int q0, int c0, int wave, int lane, int la, int qd,
                                        short8 (&qhi)[2][2], short8 (&qlo)[2][2],
                                        short8 (&kH)[2][2][2], short8 (&kL)[2][2][2],
                                        short8 (&vB)[2][4], f4 (&cacc)[2][4]) {
    f4 s[2][2] = {};
#pragma unroll
    for (int n2 = 0; n2 < 2; ++n2)
#pragma unroll
        for (int ks = 0; ks < 2; ++ks)
#pragma unroll
            for (int ms = 0; ms < 2; ++ms) {
                s[ms][n2] = mfma16(qlo[ms][ks], kH[B][n2][ks], s[ms][n2]);
                s[ms][n2] = mfma16(qhi[ms][ks], kL[B][n2][ks], s[ms][n2]);
                s[ms][n2] = mfma16(qhi[ms][ks], kH[B][n2][ks], s[ms][n2]);
            }
    // spike -> Ps (wave-private rows)
#pragma unroll
    for (int ms = 0; ms < 2; ++ms)
#pragma unroll
        for (int n2 = 0; n2 < 2; ++n2)
#pragma unroll
            for (int r = 0; r < 4; ++r)
                Ps[wave * 32 + ms * 16 + qd * 4 + r][n2 * 16 + la] =
                    s[ms][n2][r] > 0.f ? (ushort)0x3f80 : (ushort)0;
    // attn tile: Ps readback -> widen -> dwordx4 stores (same-wave, lgkmcnt-ordered)
#pragma unroll
    for (int it = 0; it < 4; ++it) {
        int row = it * 8 + (lane >> 3);
        short4 p = *(const short4*)&Ps[wave * 32 + row][(lane & 7) * 4];
        float4 o;
        o.x = __uint_as_float(((unsigned)(ushort)p.x) << 16);
        o.y = __uint_as_float(((unsigned)(ushort)p.y) << 16);
        o.z = __uint_as_float(((unsigned)(ushort)p.z) << 16);
        o.w = __uint_as_float(((unsigned)(ushort)p.w) << 16);
        *(float4*)&attn[((size_t)bh * SEQ + q0 + row) * SEQ + c0 + (lane & 7) * 4] = o;
    }
    // ctx += P @ V over this 32-col half
    short8 pa[2];
#pragma unroll
    for (int ms = 0; ms < 2; ++ms)
        pa[ms] = *(const short8*)&Ps[wave * 32 + ms * 16 + la][qd * 8];
#pragma unroll
    for (int ns = 0; ns < 4; ++ns)
#pragma unroll
        for (int ms = 0; ms < 2; ++ms) cacc[ms][ns] = mfma16(pa[ms], vB[B][ns], cacc[ms][ns]);
}

__global__ __launch_bounds__(256, 2) void attn_mfma(
    const ushort* __restrict__ Qhi, const ushort* __restrict__ Qlo,
    const ushort* __restrict__ Khi, const ushort* __restrict__ Klo,
    const ushort* __restrict__ Vt, float* __restrict__ attn, ushort* __restrict__ ctxb) {
    __shared__ ushort Ps[128][40];
    const int t = threadIdx.x, wave = t >> 6, lane = t & 63;
    const int la = lane & 15, qd = lane >> 4;
    const int bh = blockIdx.x;
    const int q0 = blockIdx.y * 128 + wave * 32;

    short8 qhi[2][2], qlo[2][2];
#pragma unroll
    for (int ms = 0; ms < 2; ++ms)
#pragma unroll
        for (int ks = 0; ks < 2; ++ks) {
            size_t qi = ((size_t)bh * SEQ + q0 + ms * 16 + la) * HD + ks * 32 + qd * 8;
            qhi[ms][ks] = ld8(&Qhi[qi]);
            qlo[ms][ks] = ld8(&Qlo[qi]);
        }

    short8 kH[2][2][2], kL[2][2][2], vB[2][4];
    f4 cacc[2][4] = {};
    ld_at<0>(Khi, Klo, Vt, bh, 0, la, qd, kH, kL, vB);
    for (int h = 0; h < 64; h += 2) {
        ld_at<1>(Khi, Klo, Vt, bh, (h + 1) * 32, la, qd, kH, kL, vB);
        half_at<0>(Ps, attn, bh, q0, h * 32, wave, lane, la, qd, qhi, qlo, kH, kL, vB, cacc);
        ld_at<0>(Khi, Klo, Vt, bh, ((h + 2) & 63) * 32, la, qd, kH, kL, vB);
        half_at<1>(Ps, attn, bh, q0, (h + 1) * 32, wave, lane, la, qd, qhi, qlo, kH, kL, vB, cacc);
    }
#pragma unroll
    for (int ns = 0; ns < 4; ++ns)
#pragma unroll
        for (int ms = 0; ms < 2; ++ms)
#pragma unroll
            for (int r = 0; r < 4; ++r) {
                int qrow = q0 + ms * 16 + qd * 4 + r;
                ctxb[((size_t)bh * SEQ + qrow) * HD + ns * 16 + la] = rne16(cacc[ms][ns][r]);
            }
}

// ---------- out projection, pipelined ----------
template <int B>
__device__ __forceinline__ void ld_o(const ushort* __restrict__ Ctx, const ushort* __restrict__ Wb,
                                     int m0, int n0, int la, int qd, int k0,
                                     short8 (&aO)[2][2], short8 (&wO)[2][4]) {
#pragma unroll
    for (int ms = 0; ms < 2; ++ms) {
        int m = m0 + ms * 16 + la;
        int b = m >> 11, s = m & 2047;
        int k = k0 + qd * 8;
        int h = k >> 6, d = k & 63;
        aO[B][ms] = ld8(&Ctx[((size_t)(b * NH + h) * SEQ + s) * HD + d]);
    }
#pragma unroll
    for (int ns = 0; ns < 4; ++ns)
        wO[B][ns] = ld8(&Wb[(size_t)(n0 + ns * 16 + la) * DIM + k0 + qd * 8]);
}

__global__ __launch_bounds__(256, 2) void proj_out(const ushort* __restrict__ Ctx,
                                                   const ushort* __restrict__ Wb,
                                                   const float* __restrict__ bias,
                                                   float* __restrict__ out) {
    const int t = threadIdx.x, wave = t >> 6, lane = t & 63;
    const int la = lane & 15, qd = lane >> 4;
    const int m0 = blockIdx.x * 128 + wave * 32;
    const int n0 = blockIdx.y * 64;

    short8 aO[2][2], wO[2][4];
    f4 acc[2][4] = {};
    ld_o<0>(Ctx, Wb, m0, n0, la, qd, 0, aO, wO);
    for (int k0 = 0; k0 < DIM; k0 += 64) {
        ld_o<1>(Ctx, Wb, m0, n0, la, qd, k0 + 32, aO, wO);
#pragma unroll
        for (int ns = 0; ns < 4; ++ns)
#pragma unroll
            for (int ms = 0; ms < 2; ++ms) acc[ms][ns] = mfma16(aO[0][ms], wO[0][ns], acc[ms][ns]);
        ld_o<0>(Ctx, Wb, m0, n0, la, qd, (k0 + 64) & (DIM - 1), aO, wO);
#pragma unroll
        for (int ns = 0; ns < 4; ++ns)
#pragma unroll
            for (int ms = 0; ms < 2; ++ms) acc[ms][ns] = mfma16(aO[1][ms], wO[1][ns], acc[ms][ns]);
    }
#pragma unroll
    for (int ns = 0; ns < 4; ++ns) {
        int n = n0 + ns * 16 + la;
        float bvv = bias[n];
#pragma unroll
        for (int ms = 0; ms < 2; ++ms)
#pragma unroll
            for (int r = 0; r < 4; ++r) {
                int m = m0 + ms * 16 + qd * 4 + r;
                out[(size_t)m * DIM + n] = acc[ms][ns][r] + bvv;
            }
    }
}

extern "C" void kernel_launch(void* const* d_in, const int* in_sizes, int n_in,
                              void* d_out, int out_size, void* d_ws, size_t ws_size,
                              hipStream_t stream) {
    const float* query = (const float*)d_in[0];
    const float* key   = (const float*)d_in[1];
    const float* value = (const float*)d_in[2];
    const float* Wq = (const float*)d_in[3];
    const float* bq = (const float*)d_in[4];
    const float* Wk = (const float*)d_in[5];
    const float* bk = (const float*)d_in[6];
    const float* Wv = (const float*)d_in[7];
    const float* bv = (const float*)d_in[8];
    const float* Wo = (const float*)d_in[9];
    const float* bo = (const float*)d_in[10];

    float* out  = (float*)d_out;
    float* attn = out + (size_t)MROWS * DIM;

    const size_t NE = (size_t)MROWS * DIM;  // 4,194,304
    const size_t WE = (size_t)DIM * DIM;    // 1,048,576
    ushort* Qhi = (ushort*)d_ws;            // 5 x NE = 40 MiB
    ushort* Qlo = Qhi + NE;
    ushort* Khi = Qlo + NE;
    ushort* Klo = Khi + NE;
    ushort* Vt  = Klo + NE;
    ushort* Wqh = Vt + NE;                  // 6 x WE = 12 MiB
    ushort* Wql = Wqh + WE;
    ushort* Wkh = Wql + WE;
    ushort* Wkl = Wkh + WE;
    ushort* Wvb = Wkl + WE;
    ushort* Wob = Wvb + WE;
    ushort* Ctx = Wqh;                      // overlays Wqh..Wkl (dead after proj_qkv)

    dim3 blk(256);
    hipLaunchKernelGGL(wconv, dim3(WE / 1024, 4), blk, 0, stream,
                       Wq, Wk, Wv, Wo, Wqh, Wql, Wkh, Wkl, Wvb, Wob);
    hipLaunchKernelGGL(proj_qkv, dim3(32, 16, 3), blk, 0, stream,
                       query, key, value, Wqh, Wql, Wkh, Wkl, Wvb, bq, bk, bv,
                       Qhi, Qlo, Khi, Klo, Vt);
    hipLaunchKernelGGL(attn_mfma, dim3(32, 16), blk, 0, stream,
                       Qhi, Qlo, Khi, Klo, Vt, attn, Ctx);
    hipLaunchKernelGGL(proj_out, dim3(32, 16), blk, 0, stream, Ctx, Wob, bo, out);
}